// Round 1
// baseline (1314.736 us; speedup 1.0000x reference)
//
#include <hip/hip_runtime.h>
#include <math.h>

// Problem constants
static constexpr int NB   = 8;     // batch
static constexpr int SEQ  = 1024;  // sequence length
static constexpr int TD   = 768;   // token dim
static constexpr int NH   = 12;    // heads
static constexpr int HD   = 64;    // head dim
static constexpr int QKVC = 3 * NH * HD;  // 2304

// ---------------------------------------------------------------------------
// Generic fp32 tiled GEMM: C[M,N] = A[M,K] @ B[K,N] (+ bias if BIAS)
// 64x64 tile, BK=16, 256 threads, 4x4 per thread.
// ---------------------------------------------------------------------------
template <int BIAS>
__global__ __launch_bounds__(256) void gemm_f32(const float* __restrict__ A,
                                                const float* __restrict__ B,
                                                const float* __restrict__ bias,
                                                float* __restrict__ C,
                                                int M, int N, int K) {
  __shared__ float As[16][65];  // As[k][m]
  __shared__ float Bs[16][65];  // Bs[k][n]
  const int tid = threadIdx.x;
  const int tx = tid & 15;   // n direction (16 groups of 4)
  const int ty = tid >> 4;   // m direction (16 groups of 4)
  const int bm = blockIdx.y * 64;
  const int bn = blockIdx.x * 64;

  float acc[4][4] = {};
  for (int k0 = 0; k0 < K; k0 += 16) {
#pragma unroll
    for (int i = 0; i < 4; ++i) {
      int idx = tid + i * 256;
      int m = idx >> 4, k = idx & 15;
      As[k][m] = A[(size_t)(bm + m) * K + k0 + k];
    }
#pragma unroll
    for (int i = 0; i < 4; ++i) {
      int idx = tid + i * 256;
      int k = idx >> 6, n = idx & 63;
      Bs[k][n] = B[(size_t)(k0 + k) * N + bn + n];
    }
    __syncthreads();
#pragma unroll
    for (int k = 0; k < 16; ++k) {
      float a[4], b[4];
#pragma unroll
      for (int i = 0; i < 4; ++i) a[i] = As[k][ty * 4 + i];
#pragma unroll
      for (int j = 0; j < 4; ++j) b[j] = Bs[k][tx * 4 + j];
#pragma unroll
      for (int i = 0; i < 4; ++i)
#pragma unroll
        for (int j = 0; j < 4; ++j) acc[i][j] = fmaf(a[i], b[j], acc[i][j]);
    }
    __syncthreads();
  }
#pragma unroll
  for (int i = 0; i < 4; ++i) {
    int m = bm + ty * 4 + i;
#pragma unroll
    for (int j = 0; j < 4; ++j) {
      int n = bn + tx * 4 + j;
      float v = acc[i][j];
      if (BIAS) v += bias[n];
      C[(size_t)m * N + n] = v;
    }
  }
}

// ---------------------------------------------------------------------------
// Flash-style fp32 attention.
// Reference quirk: qkv.reshape(b,3,H,n,D) reinterprets the per-batch (N,2304)
// row-major buffer as 3 contiguous thirds, each a contiguous (H,N,D) block.
// So per (b,h): Q/K/V are contiguous (1024,64) matrices at
//   qkv + b*3*NH*SEQ*HD + t*NH*SEQ*HD + h*SEQ*HD.
// Block = (q-tile of 64 rows, h, b); 256 threads; KV-tile = 32.
// Output written as attn2[(b*SEQ+n)*768 + h*64 + d]  (transpose-concat).
// ---------------------------------------------------------------------------
__global__ __launch_bounds__(256) void flash_attn_f32(
    const float* __restrict__ qkv, float* __restrict__ attn2) {
  const int qt = blockIdx.x;  // 0..15
  const int h = blockIdx.y;   // 0..11
  const int b = blockIdx.z;   // 0..7
  const int tid = threadIdx.x;
  const int tx = tid & 15;
  const int ty = tid >> 4;

  __shared__ float Qs[64][65];
  __shared__ float Ks[32][65];
  __shared__ float Vs[32][64];
  __shared__ float Ss[64][33];
  __shared__ float rowm[64], rowl[64], rowa[64];

  const size_t base = (size_t)b * (3 * NH * SEQ * HD);
  const float* Q = qkv + base + (size_t)h * (SEQ * HD);
  const float* K = qkv + base + (size_t)NH * SEQ * HD + (size_t)h * (SEQ * HD);
  const float* V = qkv + base + (size_t)2 * NH * SEQ * HD + (size_t)h * (SEQ * HD);
  const int q0 = qt * 64;

  // Load Q tile: 64x64 = 4096 elems, 16 per thread
#pragma unroll
  for (int i = 0; i < 16; ++i) {
    int idx = tid + i * 256;
    int m = idx >> 6, d = idx & 63;
    Qs[m][d] = Q[(size_t)(q0 + m) * HD + d];
  }
  if (tid < 64) {
    rowm[tid] = -INFINITY;
    rowl[tid] = 0.f;
  }
  __syncthreads();

  float O[4][4] = {};  // O[r=ty*4+i][d=tx*4+j]

  for (int kt = 0; kt < SEQ; kt += 32) {
    // Load K,V tiles: 32x64 each, 8 per thread
#pragma unroll
    for (int i = 0; i < 8; ++i) {
      int idx = tid + i * 256;
      int m = idx >> 6, d = idx & 63;
      Ks[m][d] = K[(size_t)(kt + m) * HD + d];
      Vs[m][d] = V[(size_t)(kt + m) * HD + d];
    }
    __syncthreads();

    // S[r][c] = 0.125 * sum_d Qs[r][d]*Ks[c][d];  r in 64, c in 32
    {
      float sacc[4][2] = {};
      for (int d = 0; d < 64; ++d) {
        float qv[4], kv[2];
#pragma unroll
        for (int i = 0; i < 4; ++i) qv[i] = Qs[ty * 4 + i][d];
#pragma unroll
        for (int j = 0; j < 2; ++j) kv[j] = Ks[tx * 2 + j][d];
#pragma unroll
        for (int i = 0; i < 4; ++i)
#pragma unroll
          for (int j = 0; j < 2; ++j) sacc[i][j] = fmaf(qv[i], kv[j], sacc[i][j]);
      }
#pragma unroll
      for (int i = 0; i < 4; ++i)
#pragma unroll
        for (int j = 0; j < 2; ++j)
          Ss[ty * 4 + i][tx * 2 + j] = sacc[i][j] * 0.125f;
    }
    __syncthreads();

    // Per-row online softmax stats (threads 0..63, one row each)
    if (tid < 64) {
      float m0 = rowm[tid];
      float tmax = -INFINITY;
      for (int c = 0; c < 32; ++c) tmax = fmaxf(tmax, Ss[tid][c]);
      float nm = fmaxf(m0, tmax);
      float a = __expf(m0 - nm);  // 0 on first tile (m0=-inf)
      float s = 0.f;
      for (int c = 0; c < 32; ++c) {
        float p = __expf(Ss[tid][c] - nm);
        Ss[tid][c] = p;
        s += p;
      }
      rowl[tid] = rowl[tid] * a + s;
      rowm[tid] = nm;
      rowa[tid] = a;
    }
    __syncthreads();

    // O = O*alpha(row) + P(64x32) @ V(32x64)
    {
      float a[4];
#pragma unroll
      for (int i = 0; i < 4; ++i) a[i] = rowa[ty * 4 + i];
#pragma unroll
      for (int i = 0; i < 4; ++i)
#pragma unroll
        for (int j = 0; j < 4; ++j) O[i][j] *= a[i];
      for (int kk = 0; kk < 32; ++kk) {
        float pv[4], vv[4];
#pragma unroll
        for (int i = 0; i < 4; ++i) pv[i] = Ss[ty * 4 + i][kk];
#pragma unroll
        for (int j = 0; j < 4; ++j) vv[j] = Vs[kk][tx * 4 + j];
#pragma unroll
        for (int i = 0; i < 4; ++i)
#pragma unroll
          for (int j = 0; j < 4; ++j) O[i][j] = fmaf(pv[i], vv[j], O[i][j]);
      }
    }
    __syncthreads();  // protect Ks/Vs/Ss before next iteration
  }

  // Finalize + write attn2[(b*SEQ + q0+r)*768 + h*64 + d]
#pragma unroll
  for (int i = 0; i < 4; ++i) {
    int r = ty * 4 + i;
    float inv = 1.0f / rowl[r];
#pragma unroll
    for (int j = 0; j < 4; ++j) {
      int d = tx * 4 + j;
      attn2[(size_t)(b * SEQ + q0 + r) * (NH * HD) + h * HD + d] = O[i][j] * inv;
    }
  }
}

// ---------------------------------------------------------------------------
extern "C" void kernel_launch(void* const* d_in, const int* in_sizes, int n_in,
                              void* d_out, int out_size, void* d_ws,
                              size_t ws_size, hipStream_t stream) {
  const float* x = (const float*)d_in[0];      // (8,1024,768)
  const float* W_qkv = (const float*)d_in[1];  // (768,2304)
  const float* W_out = (const float*)d_in[2];  // (768,768)
  const float* b_out = (const float*)d_in[3];  // (768,)
  float* out = (float*)d_out;                  // (8,1024,768) fp32

  // Workspace layout (needs ~101 MB):
  //   qkv   : 8*1024*2304 fp32 = 75.5 MB
  //   attn2 : 8*1024*768  fp32 = 25.2 MB
  float* qkv = (float*)d_ws;
  float* attn2 = qkv + (size_t)NB * SEQ * QKVC;

  // GEMM1: (8192 x 768) @ (768 x 2304) -> qkv
  {
    dim3 grid(QKVC / 64, (NB * SEQ) / 64);
    hipLaunchKernelGGL((gemm_f32<0>), grid, dim3(256), 0, stream, x, W_qkv,
                       nullptr, qkv, NB * SEQ, QKVC, TD);
  }
  // Flash attention -> attn2
  {
    dim3 grid(SEQ / 64, NH, NB);
    hipLaunchKernelGGL(flash_attn_f32, grid, dim3(256), 0, stream, qkv, attn2);
  }
  // GEMM2: (8192 x 768) @ (768 x 768) + bias -> out
  {
    dim3 grid(TD / 64, (NB * SEQ) / 64);
    hipLaunchKernelGGL((gemm_f32<1>), grid, dim3(256), 0, stream, attn2, W_out,
                       b_out, out, NB * SEQ, TD, TD);
  }
}

// Round 4
// 190.865 us; speedup vs baseline: 6.8883x; 6.8883x over previous
//
#include <hip/hip_runtime.h>
#include <math.h>

// Problem constants
static constexpr int NB   = 8;     // batch
static constexpr int SEQ  = 1024;  // sequence length
static constexpr int TD   = 768;   // token dim
static constexpr int NH   = 12;    // heads
static constexpr int HD   = 64;    // head dim
static constexpr int QKVC = 3 * NH * HD;  // 2304

// Reference reshape quirk: qkv.reshape(b,3,H,n,D) reinterprets the per-batch
// flat (N*2304) row-major buffer as contiguous thirds. Per (b, t, h):
//   elem(t,h,n,d) = qkv_flat[b*2359296 + t*786432 + h*65536 + n*64 + d]
// So Q/K/V per (b,h) are contiguous (1024,64) bf16 matrices.
static constexpr size_t BATCH_ELEMS = (size_t)SEQ * QKVC;   // 2359296
static constexpr size_t THIRD_ELEMS = (size_t)NH * SEQ * HD; // 786432
static constexpr size_t HEAD_ELEMS  = (size_t)SEQ * HD;      // 65536

typedef __bf16 bf16x8 __attribute__((ext_vector_type(8)));
typedef __bf16 bf16x4 __attribute__((ext_vector_type(4)));
typedef float  f32x4  __attribute__((ext_vector_type(4)));

#define MFMA16(a, b, c) __builtin_amdgcn_mfma_f32_16x16x32_bf16((a), (b), (c), 0, 0, 0)

// ---------------------------------------------------------------------------
// cast fp32 -> bf16, 4 elems/thread
// ---------------------------------------------------------------------------
__global__ __launch_bounds__(256) void cast_f32_bf16(const float* __restrict__ in,
                                                     __bf16* __restrict__ out, int n4) {
  int i = blockIdx.x * 256 + threadIdx.x;
  if (i < n4) {
    float4 v = ((const float4*)in)[i];
    bf16x4 o;
    o[0] = (__bf16)v.x; o[1] = (__bf16)v.y; o[2] = (__bf16)v.z; o[3] = (__bf16)v.w;
    ((bf16x4*)out)[i] = o;
  }
}

// ---------------------------------------------------------------------------
// transpose + cast: W (K x N f32) -> Wt (N x K bf16). 32x32 tiles.
// ---------------------------------------------------------------------------
__global__ __launch_bounds__(256) void wtrans(const float* __restrict__ W,
                                              __bf16* __restrict__ Wt, int K, int N) {
  __shared__ float T[32 * 33];
  const int tid = threadIdx.x;
  const int k0 = blockIdx.y * 32, n0 = blockIdx.x * 32;
#pragma unroll
  for (int i = 0; i < 4; ++i) {
    int idx = tid + i * 256;
    int kk = idx >> 5, nn = idx & 31;
    T[kk * 33 + nn] = W[(size_t)(k0 + kk) * N + n0 + nn];
  }
  __syncthreads();
#pragma unroll
  for (int i = 0; i < 4; ++i) {
    int idx = tid + i * 256;
    int nn = idx >> 5, kk = idx & 31;
    Wt[(size_t)(n0 + nn) * K + k0 + kk] = (__bf16)T[kk * 33 + nn];
  }
}

// ---------------------------------------------------------------------------
// Transpose V third: per (b,h), V is a contiguous (1024,64) bf16 block at
//   qkvb + b*BATCH + 2*THIRD + h*HEAD.
// Produce Vt[b][h][d][n] (d-major, n contiguous) for the PV B-fragments.
// Block handles a 128-row n-tile; LDS tile [128 n][72 pad] bf16.
// ---------------------------------------------------------------------------
__global__ __launch_bounds__(256) void vtrans(const __bf16* __restrict__ qkvb,
                                              __bf16* __restrict__ vtb) {
  const int nt = blockIdx.x;  // 0..7
  const int h = blockIdx.y;   // 0..11
  const int b = blockIdx.z;   // 0..7
  __shared__ __bf16 T[128 * 72];
  const int tid = threadIdx.x;
  const int n0 = nt * 128;
  const __bf16* Vb = qkvb + (size_t)b * BATCH_ELEMS + 2 * THIRD_ELEMS + (size_t)h * HEAD_ELEMS;
#pragma unroll
  for (int i = 0; i < 4; ++i) {
    int ch = tid + i * 256;
    int row = ch >> 3, c8 = ch & 7;
    *(bf16x8*)&T[row * 72 + c8 * 8] = *(const bf16x8*)&Vb[(size_t)(n0 + row) * HD + c8 * 8];
  }
  __syncthreads();
#pragma unroll
  for (int i = 0; i < 4; ++i) {
    int ch = tid + i * 256;
    int d = ch >> 4, n8 = ch & 15;
    bf16x8 v;
#pragma unroll
    for (int j = 0; j < 8; ++j) v[j] = T[(n8 * 8 + j) * 72 + d];
    *(bf16x8*)&vtb[((size_t)((b * NH + h) * HD) + d) * SEQ + n0 + n8 * 8] = v;
  }
}

// ---------------------------------------------------------------------------
// bf16 MFMA GEMM: C[M,N] = A[M,K] @ Bt[N,K]^T  (+ bias, fp32 out) or bf16 out.
// 128x128 tile, BK=32, 256 threads = 4 waves (2x2 of 64x64).
// LDS rows padded to 40 bf16 (80B): 16B-aligned b128 reads, free 2-way banks.
// ---------------------------------------------------------------------------
template <int OUT_BF16>
__global__ __launch_bounds__(256) void gemm_mfma(const __bf16* __restrict__ A,
                                                 const __bf16* __restrict__ Bt,
                                                 const float* __restrict__ bias,
                                                 void* __restrict__ C,
                                                 int M, int N, int K) {
  __shared__ __bf16 As[128 * 40];
  __shared__ __bf16 Bs[128 * 40];
  const int tid = threadIdx.x;
  const int lane = tid & 63;
  const int wid = tid >> 6;
  const int wr = wid >> 1, wc = wid & 1;
  const int r = lane & 15, g = lane >> 4;
  const size_t bm = (size_t)blockIdx.y * 128;
  const size_t bn = (size_t)blockIdx.x * 128;

  f32x4 acc[4][4];
#pragma unroll
  for (int mi = 0; mi < 4; ++mi)
#pragma unroll
    for (int nj = 0; nj < 4; ++nj) acc[mi][nj] = (f32x4){0.f, 0.f, 0.f, 0.f};

  for (int k0 = 0; k0 < K; k0 += 32) {
#pragma unroll
    for (int i = 0; i < 2; ++i) {
      int ch = tid + i * 256;
      int row = ch >> 2, c8 = ch & 3;
      *(bf16x8*)&As[row * 40 + c8 * 8] =
          *(const bf16x8*)&A[(bm + row) * K + k0 + c8 * 8];
      *(bf16x8*)&Bs[row * 40 + c8 * 8] =
          *(const bf16x8*)&Bt[(bn + row) * K + k0 + c8 * 8];
    }
    __syncthreads();
    bf16x8 af[4], bf[4];
#pragma unroll
    for (int mi = 0; mi < 4; ++mi)
      af[mi] = *(const bf16x8*)&As[(wr * 64 + mi * 16 + r) * 40 + g * 8];
#pragma unroll
    for (int nj = 0; nj < 4; ++nj)
      bf[nj] = *(const bf16x8*)&Bs[(wc * 64 + nj * 16 + r) * 40 + g * 8];
#pragma unroll
    for (int mi = 0; mi < 4; ++mi)
#pragma unroll
      for (int nj = 0; nj < 4; ++nj)
        acc[mi][nj] = MFMA16(af[mi], bf[nj], acc[mi][nj]);
    __syncthreads();
  }

  const int orow0 = g * 4;
  const int ocol = r;
#pragma unroll
  for (int mi = 0; mi < 4; ++mi)
#pragma unroll
    for (int nj = 0; nj < 4; ++nj)
#pragma unroll
      for (int reg = 0; reg < 4; ++reg) {
        size_t rrow = bm + wr * 64 + mi * 16 + orow0 + reg;
        size_t ccol = bn + wc * 64 + nj * 16 + ocol;
        float v = acc[mi][nj][reg];
        if (OUT_BF16)
          ((__bf16*)C)[rrow * N + ccol] = (__bf16)v;
        else
          ((float*)C)[rrow * N + ccol] = v + bias[ccol];
      }
}

// ---------------------------------------------------------------------------
// bf16 MFMA flash attention (contiguous-thirds Q/K/V indexing).
// Block = (q-tile 64, h, b); 4 waves; each wave owns 16 q rows.
// KV-tile 64 staged in LDS ([64][72] pad). Vt pre-transposed: Vs rows = d.
// Online softmax per D-layout: lane group g tracks rows g*4+reg; reduce via
// shfl_xor masks 1,2,4,8 (within 16-lane group). P re-layout via per-wave LDS.
// P tile per wave is 16 rows x 64 kv cols -> stride 72 (NOT 40; that was the
// round-2/3 corruption bug).
// ---------------------------------------------------------------------------
__global__ __launch_bounds__(256) void attn_mfma(const __bf16* __restrict__ qkvb,
                                                 const __bf16* __restrict__ vtb,
                                                 __bf16* __restrict__ attn2b) {
  const int qt = blockIdx.x;  // 0..15
  const int h = blockIdx.y;   // 0..11
  const int b = blockIdx.z;   // 0..7
  const int tid = threadIdx.x;
  const int lane = tid & 63;
  const int wid = tid >> 6;
  const int c = lane & 15, g = lane >> 4;

  __shared__ __bf16 Ks[64 * 72];
  __shared__ __bf16 Vs[64 * 72];
  __shared__ __bf16 Ps[4][16 * 72];

  const __bf16* Qb = qkvb + (size_t)b * BATCH_ELEMS + (size_t)h * HEAD_ELEMS;
  const __bf16* Kb = Qb + THIRD_ELEMS;
  const int q0 = qt * 64 + wid * 16;

  // Q A-frags (rows q0+c, k-slices): 2 frags cover d=0..63
  bf16x8 qf[2];
#pragma unroll
  for (int f = 0; f < 2; ++f)
    qf[f] = *(const bf16x8*)&Qb[(size_t)(q0 + c) * HD + f * 32 + g * 8];

  f32x4 O[4];
#pragma unroll
  for (int db = 0; db < 4; ++db) O[db] = (f32x4){0.f, 0.f, 0.f, 0.f};
  float mrow[4], lrow[4];
#pragma unroll
  for (int reg = 0; reg < 4; ++reg) { mrow[reg] = -3.0e38f; lrow[reg] = 0.f; }

  for (int kv0 = 0; kv0 < SEQ; kv0 += 64) {
    // stage K rows (kv, d) and Vt rows (d, kv)
#pragma unroll
    for (int i = 0; i < 2; ++i) {
      int ch = tid + i * 256;
      int row = ch >> 3, c8 = ch & 7;
      *(bf16x8*)&Ks[row * 72 + c8 * 8] =
          *(const bf16x8*)&Kb[(size_t)(kv0 + row) * HD + c8 * 8];
      *(bf16x8*)&Vs[row * 72 + c8 * 8] =
          *(const bf16x8*)&vtb[((size_t)((b * NH + h) * HD) + row) * SEQ + kv0 + c8 * 8];
    }
    __syncthreads();

    // S = 0.125 * Q K^T : 4 col-blocks of 16 kv
    f32x4 s[4];
#pragma unroll
    for (int cb = 0; cb < 4; ++cb) s[cb] = (f32x4){0.f, 0.f, 0.f, 0.f};
#pragma unroll
    for (int cb = 0; cb < 4; ++cb)
#pragma unroll
      for (int f = 0; f < 2; ++f) {
        bf16x8 kf = *(const bf16x8*)&Ks[(cb * 16 + c) * 72 + f * 32 + g * 8];
        s[cb] = MFMA16(qf[f], kf, s[cb]);
      }
#pragma unroll
    for (int cb = 0; cb < 4; ++cb)
#pragma unroll
      for (int reg = 0; reg < 4; ++reg) s[cb][reg] *= 0.125f;

    // online softmax stats; lane-group g owns rows g*4+reg
    float tm[4], alpha[4], rs[4];
#pragma unroll
    for (int reg = 0; reg < 4; ++reg) {
      tm[reg] = fmaxf(fmaxf(s[0][reg], s[1][reg]), fmaxf(s[2][reg], s[3][reg]));
    }
#pragma unroll
    for (int m = 1; m <= 8; m <<= 1)
#pragma unroll
      for (int reg = 0; reg < 4; ++reg)
        tm[reg] = fmaxf(tm[reg], __shfl_xor(tm[reg], m));
#pragma unroll
    for (int reg = 0; reg < 4; ++reg) {
      float mn = fmaxf(mrow[reg], tm[reg]);
      alpha[reg] = __expf(mrow[reg] - mn);
      mrow[reg] = mn;
      rs[reg] = 0.f;
    }
#pragma unroll
    for (int cb = 0; cb < 4; ++cb)
#pragma unroll
      for (int reg = 0; reg < 4; ++reg) {
        float p = __expf(s[cb][reg] - mrow[reg]);
        s[cb][reg] = p;
        rs[reg] += p;
      }
#pragma unroll
    for (int m = 1; m <= 8; m <<= 1)
#pragma unroll
      for (int reg = 0; reg < 4; ++reg) rs[reg] += __shfl_xor(rs[reg], m);
#pragma unroll
    for (int reg = 0; reg < 4; ++reg) lrow[reg] = lrow[reg] * alpha[reg] + rs[reg];
#pragma unroll
    for (int db = 0; db < 4; ++db)
#pragma unroll
      for (int reg = 0; reg < 4; ++reg) O[db][reg] *= alpha[reg];

    // P -> per-wave LDS (row = g*4+reg, col = cb*16+c, stride 72), then A-frags
    __bf16* P = &Ps[wid][0];
#pragma unroll
    for (int cb = 0; cb < 4; ++cb)
#pragma unroll
      for (int reg = 0; reg < 4; ++reg)
        P[(g * 4 + reg) * 72 + cb * 16 + c] = (__bf16)s[cb][reg];
    __syncthreads();

    bf16x8 pa[2];
#pragma unroll
    for (int kk = 0; kk < 2; ++kk)
      pa[kk] = *(const bf16x8*)&P[c * 72 + kk * 32 + g * 8];

#pragma unroll
    for (int db = 0; db < 4; ++db)
#pragma unroll
      for (int kk = 0; kk < 2; ++kk) {
        bf16x8 vf = *(const bf16x8*)&Vs[(db * 16 + c) * 72 + kk * 32 + g * 8];
        O[db] = MFMA16(pa[kk], vf, O[db]);
      }
    __syncthreads();
  }

  // finalize + write attn2 (bf16), row=q, col=h*64+d  (standard transposed
  // concat layout: attn.transpose(0,2,1,3).reshape(b,n,768))
#pragma unroll
  for (int reg = 0; reg < 4; ++reg) {
    float inv = 1.0f / lrow[reg];
    size_t rowq = (size_t)(b * SEQ) + q0 + g * 4 + reg;
#pragma unroll
    for (int db = 0; db < 4; ++db)
      attn2b[rowq * TD + h * HD + db * 16 + c] = (__bf16)(O[db][reg] * inv);
  }
}

// ---------------------------------------------------------------------------
extern "C" void kernel_launch(void* const* d_in, const int* in_sizes, int n_in,
                              void* d_out, int out_size, void* d_ws,
                              size_t ws_size, hipStream_t stream) {
  const float* x = (const float*)d_in[0];      // (8,1024,768)
  const float* W_qkv = (const float*)d_in[1];  // (768,2304)
  const float* W_out = (const float*)d_in[2];  // (768,768)
  const float* b_out = (const float*)d_in[3];  // (768,)
  float* out = (float*)d_out;

  // Workspace (bf16 elems): xb | wqkvt | woutt | qkvb | vtb | attn2b  (~80 MB)
  __bf16* xb = (__bf16*)d_ws;
  __bf16* wqkvt = xb + (size_t)NB * SEQ * TD;           // 6291456
  __bf16* woutt = wqkvt + (size_t)QKVC * TD;            // 1769472
  __bf16* qkvb = woutt + (size_t)TD * TD;               // 589824
  __bf16* vtb = qkvb + (size_t)NB * SEQ * QKVC;         // 18874368
  __bf16* attn2b = vtb + (size_t)NB * NH * HD * SEQ;    // 6291456

  // casts / transposes
  cast_f32_bf16<<<(NB * SEQ * TD / 4 + 255) / 256, 256, 0, stream>>>(x, xb, NB * SEQ * TD / 4);
  wtrans<<<dim3(QKVC / 32, TD / 32), 256, 0, stream>>>(W_qkv, wqkvt, TD, QKVC);
  wtrans<<<dim3(TD / 32, TD / 32), 256, 0, stream>>>(W_out, woutt, TD, TD);

  // GEMM1: (8192x768) @ (768x2304) -> qkv bf16 (flat buffer == reshaped view)
  gemm_mfma<1><<<dim3(QKVC / 128, NB * SEQ / 128), 256, 0, stream>>>(
      xb, wqkvt, nullptr, qkvb, NB * SEQ, QKVC, TD);

  // V transpose (per b,h contiguous blocks)
  vtrans<<<dim3(SEQ / 128, NH, NB), 256, 0, stream>>>(qkvb, vtb);

  // attention
  attn_mfma<<<dim3(SEQ / 64, NH, NB), 256, 0, stream>>>(qkvb, vtb, attn2b);

  // GEMM2: (8192x768) @ (768x768) + bias -> out fp32
  gemm_mfma<0><<<dim3(TD / 128, NB * SEQ / 128), 256, 0, stream>>>(
      attn2b, woutt, b_out, out, NB * SEQ, TD, TD);
}

// Round 5
// 164.002 us; speedup vs baseline: 8.0166x; 1.1638x over previous
//
#include <hip/hip_runtime.h>
#include <math.h>

// Problem constants
static constexpr int NB   = 8;     // batch
static constexpr int SEQ  = 1024;  // sequence length
static constexpr int TD   = 768;   // token dim
static constexpr int NH   = 12;    // heads
static constexpr int HD   = 64;    // head dim
static constexpr int QKVC = 3 * NH * HD;  // 2304

// Reference reshape quirk: qkv.reshape(b,3,H,n,D) reinterprets the per-batch
// flat (N*2304) row-major buffer as contiguous thirds. Per (b, t, h):
//   elem(t,h,n,d) = qkv_flat[b*2359296 + t*786432 + h*65536 + n*64 + d]
static constexpr size_t BATCH_ELEMS = (size_t)SEQ * QKVC;    // 2359296
static constexpr size_t THIRD_ELEMS = (size_t)NH * SEQ * HD; // 786432
static constexpr size_t HEAD_ELEMS  = (size_t)SEQ * HD;      // 65536

typedef __bf16 bf16x8 __attribute__((ext_vector_type(8)));
typedef __bf16 bf16x4 __attribute__((ext_vector_type(4)));
typedef float  f32x4  __attribute__((ext_vector_type(4)));

#define MFMA16(a, b, c) __builtin_amdgcn_mfma_f32_16x16x32_bf16((a), (b), (c), 0, 0, 0)

// 0.125 (attention scale) * log2(e), folded into exp2
static constexpr float SCL2E = 0.18033688011112042f;

// ---------------------------------------------------------------------------
// cast fp32 -> bf16, 4 elems/thread
// ---------------------------------------------------------------------------
__global__ __launch_bounds__(256) void cast_f32_bf16(const float* __restrict__ in,
                                                     __bf16* __restrict__ out, int n4) {
  int i = blockIdx.x * 256 + threadIdx.x;
  if (i < n4) {
    float4 v = ((const float4*)in)[i];
    bf16x4 o;
    o[0] = (__bf16)v.x; o[1] = (__bf16)v.y; o[2] = (__bf16)v.z; o[3] = (__bf16)v.w;
    ((bf16x4*)out)[i] = o;
  }
}

// ---------------------------------------------------------------------------
// transpose + cast: W (K x N f32) -> Wt (N x K bf16). 32x32 tiles.
// ---------------------------------------------------------------------------
__global__ __launch_bounds__(256) void wtrans(const float* __restrict__ W,
                                              __bf16* __restrict__ Wt, int K, int N) {
  __shared__ float T[32 * 33];
  const int tid = threadIdx.x;
  const int k0 = blockIdx.y * 32, n0 = blockIdx.x * 32;
#pragma unroll
  for (int i = 0; i < 4; ++i) {
    int idx = tid + i * 256;
    int kk = idx >> 5, nn = idx & 31;
    T[kk * 33 + nn] = W[(size_t)(k0 + kk) * N + n0 + nn];
  }
  __syncthreads();
#pragma unroll
  for (int i = 0; i < 4; ++i) {
    int idx = tid + i * 256;
    int nn = idx >> 5, kk = idx & 31;
    Wt[(size_t)(n0 + nn) * K + k0 + kk] = (__bf16)T[kk * 33 + nn];
  }
}

// ---------------------------------------------------------------------------
// Transpose V third: per (b,h), V is a contiguous (1024,64) bf16 block at
//   qkvb + b*BATCH + 2*THIRD + h*HEAD.
// Produce Vt[b][h][d][n] (d-major, n contiguous) for the PV A-fragments.
// ---------------------------------------------------------------------------
__global__ __launch_bounds__(256) void vtrans(const __bf16* __restrict__ qkvb,
                                              __bf16* __restrict__ vtb) {
  const int nt = blockIdx.x;  // 0..7
  const int h = blockIdx.y;   // 0..11
  const int b = blockIdx.z;   // 0..7
  __shared__ __bf16 T[128 * 72];
  const int tid = threadIdx.x;
  const int n0 = nt * 128;
  const __bf16* Vb = qkvb + (size_t)b * BATCH_ELEMS + 2 * THIRD_ELEMS + (size_t)h * HEAD_ELEMS;
#pragma unroll
  for (int i = 0; i < 4; ++i) {
    int ch = tid + i * 256;
    int row = ch >> 3, c8 = ch & 7;
    *(bf16x8*)&T[row * 72 + c8 * 8] = *(const bf16x8*)&Vb[(size_t)(n0 + row) * HD + c8 * 8];
  }
  __syncthreads();
#pragma unroll
  for (int i = 0; i < 4; ++i) {
    int ch = tid + i * 256;
    int d = ch >> 4, n8 = ch & 15;
    bf16x8 v;
#pragma unroll
    for (int j = 0; j < 8; ++j) v[j] = T[(n8 * 8 + j) * 72 + d];
    *(bf16x8*)&vtb[((size_t)((b * NH + h) * HD) + d) * SEQ + n0 + n8 * 8] = v;
  }
}

// ---------------------------------------------------------------------------
// bf16 MFMA GEMM: C[M,N] = A[M,K] @ Bt[N,K]^T  (+ bias, fp32 out) or bf16 out.
// 128x128 tile, BK=32, 256 threads = 4 waves (2x2 of 64x64).
// ---------------------------------------------------------------------------
template <int OUT_BF16>
__global__ __launch_bounds__(256) void gemm_mfma(const __bf16* __restrict__ A,
                                                 const __bf16* __restrict__ Bt,
                                                 const float* __restrict__ bias,
                                                 void* __restrict__ C,
                                                 int M, int N, int K) {
  __shared__ __bf16 As[128 * 40];
  __shared__ __bf16 Bs[128 * 40];
  const int tid = threadIdx.x;
  const int lane = tid & 63;
  const int wid = tid >> 6;
  const int wr = wid >> 1, wc = wid & 1;
  const int r = lane & 15, g = lane >> 4;
  const size_t bm = (size_t)blockIdx.y * 128;
  const size_t bn = (size_t)blockIdx.x * 128;

  f32x4 acc[4][4];
#pragma unroll
  for (int mi = 0; mi < 4; ++mi)
#pragma unroll
    for (int nj = 0; nj < 4; ++nj) acc[mi][nj] = (f32x4){0.f, 0.f, 0.f, 0.f};

  for (int k0 = 0; k0 < K; k0 += 32) {
#pragma unroll
    for (int i = 0; i < 2; ++i) {
      int ch = tid + i * 256;
      int row = ch >> 2, c8 = ch & 3;
      *(bf16x8*)&As[row * 40 + c8 * 8] =
          *(const bf16x8*)&A[(bm + row) * K + k0 + c8 * 8];
      *(bf16x8*)&Bs[row * 40 + c8 * 8] =
          *(const bf16x8*)&Bt[(bn + row) * K + k0 + c8 * 8];
    }
    __syncthreads();
    bf16x8 af[4], bf[4];
#pragma unroll
    for (int mi = 0; mi < 4; ++mi)
      af[mi] = *(const bf16x8*)&As[(wr * 64 + mi * 16 + r) * 40 + g * 8];
#pragma unroll
    for (int nj = 0; nj < 4; ++nj)
      bf[nj] = *(const bf16x8*)&Bs[(wc * 64 + nj * 16 + r) * 40 + g * 8];
#pragma unroll
    for (int mi = 0; mi < 4; ++mi)
#pragma unroll
      for (int nj = 0; nj < 4; ++nj)
        acc[mi][nj] = MFMA16(af[mi], bf[nj], acc[mi][nj]);
    __syncthreads();
  }

  const int orow0 = g * 4;
  const int ocol = r;
#pragma unroll
  for (int mi = 0; mi < 4; ++mi)
#pragma unroll
    for (int nj = 0; nj < 4; ++nj)
#pragma unroll
      for (int reg = 0; reg < 4; ++reg) {
        size_t rrow = bm + wr * 64 + mi * 16 + orow0 + reg;
        size_t ccol = bn + wc * 64 + nj * 16 + ocol;
        float v = acc[mi][nj][reg];
        if (OUT_BF16)
          ((__bf16*)C)[rrow * N + ccol] = (__bf16)v;
        else
          ((float*)C)[rrow * N + ccol] = v + bias[ccol];
      }
}

// ---------------------------------------------------------------------------
// bf16 MFMA flash attention, swapped-QK^T / in-register-P version.
//
// Per wave (16 q rows): compute S^T = mfma(A=K-frag, B=Q-frag) with K rows
// permuted per tile t: krow = (t>>1)*32 + (r>>2)*8 + (t&1)*4 + (r&3).
// With D-layout (col=lane&15, row=(lane>>4)*4+reg), lane (c,g) then holds
//   P[q = c][kv = kk*32 + g*8 + i]  for i = 0..7   (kk = t>>1, i = (t&1)*4+reg)
// which is EXACTLY the PV B-fragment layout -> P stays in registers.
// Softmax: per-lane scalar m/l (one q-row per lane), cross-g reduce via
// shfl_xor 16/32. PV: O^T = mfma(A=V^T-frag from Vs, B=pb), giving
// O^T[d = db*16 + g*4 + reg][q = c] -> coalesced bf16x4 output stores.
// No P LDS buffer, no mid-loop barrier, LDS = 18.4 KB.
// ---------------------------------------------------------------------------
__global__ __launch_bounds__(256) void attn_mfma(const __bf16* __restrict__ qkvb,
                                                 const __bf16* __restrict__ vtb,
                                                 __bf16* __restrict__ attn2b) {
  const int qt = blockIdx.x;  // 0..15
  const int h = blockIdx.y;   // 0..11
  const int b = blockIdx.z;   // 0..7
  const int tid = threadIdx.x;
  const int lane = tid & 63;
  const int wid = tid >> 6;
  const int c = lane & 15, g = lane >> 4;

  __shared__ __bf16 Ks[64 * 72];
  __shared__ __bf16 Vs[64 * 72];

  const __bf16* Qb = qkvb + (size_t)b * BATCH_ELEMS + (size_t)h * HEAD_ELEMS;
  const __bf16* Kb = Qb + THIRD_ELEMS;
  const __bf16* Vtb = vtb + (size_t)((b * NH + h) * HD) * SEQ;
  const int q0 = qt * 64 + wid * 16;

  // Q B-frags (lane c+16g holds Q[q0+c][f*32 + g*8 + i]) — natural load
  bf16x8 qf[2];
#pragma unroll
  for (int f = 0; f < 2; ++f)
    qf[f] = *(const bf16x8*)&Qb[(size_t)(q0 + c) * HD + f * 32 + g * 8];

  f32x4 Oa[4];  // O^T accum: Oa[db][reg] = O[q=c][d = db*16 + g*4 + reg]
#pragma unroll
  for (int db = 0; db < 4; ++db) Oa[db] = (f32x4){0.f, 0.f, 0.f, 0.f};
  float mrow = -3.0e38f, lrow = 0.f;

  const int rbase = ((c >> 2) << 3) | (c & 3);  // permuted K-row base

  for (int kv0 = 0; kv0 < SEQ; kv0 += 64) {
    // stage K rows (kv, d) and V^T rows (d, kv)
#pragma unroll
    for (int i = 0; i < 2; ++i) {
      int ch = tid + i * 256;
      int row = ch >> 3, c8 = ch & 7;
      *(bf16x8*)&Ks[row * 72 + c8 * 8] =
          *(const bf16x8*)&Kb[(size_t)(kv0 + row) * HD + c8 * 8];
      *(bf16x8*)&Vs[row * 72 + c8 * 8] =
          *(const bf16x8*)&Vtb[(size_t)row * SEQ + kv0 + c8 * 8];
    }
    __syncthreads();

    // S^T tiles: sa[t][reg] = S[q=c][kv = (t>>1)*32 + g*8 + (t&1)*4 + reg]
    f32x4 sa[4];
#pragma unroll
    for (int t = 0; t < 4; ++t) sa[t] = (f32x4){0.f, 0.f, 0.f, 0.f};
#pragma unroll
    for (int t = 0; t < 4; ++t) {
      const int krow = rbase + ((t >> 1) << 5) + ((t & 1) << 2);
#pragma unroll
      for (int f = 0; f < 2; ++f) {
        bf16x8 kf = *(const bf16x8*)&Ks[krow * 72 + f * 32 + g * 8];
        sa[t] = MFMA16(kf, qf[f], sa[t]);
      }
    }

    // online softmax: lane owns q-row c; its 16 kv values + cross-g reduce
    float tm = -3.0e38f;
#pragma unroll
    for (int t = 0; t < 4; ++t)
#pragma unroll
      for (int reg = 0; reg < 4; ++reg) tm = fmaxf(tm, sa[t][reg]);
    tm = fmaxf(tm, __shfl_xor(tm, 16));
    tm = fmaxf(tm, __shfl_xor(tm, 32));
    const float mnew = fmaxf(mrow, tm);
    const float alpha = __builtin_exp2f((mrow - mnew) * SCL2E);
    float rs = 0.f;
    float p[4][4];
#pragma unroll
    for (int t = 0; t < 4; ++t)
#pragma unroll
      for (int reg = 0; reg < 4; ++reg) {
        float pv = __builtin_exp2f((sa[t][reg] - mnew) * SCL2E);
        p[t][reg] = pv;
        rs += pv;
      }
    rs += __shfl_xor(rs, 16);
    rs += __shfl_xor(rs, 32);
    lrow = lrow * alpha + rs;
    mrow = mnew;
#pragma unroll
    for (int db = 0; db < 4; ++db)
#pragma unroll
      for (int reg = 0; reg < 4; ++reg) Oa[db][reg] *= alpha;

    // pack P into PV B-frags: pb[kk][i] = P[c][kv0 + kk*32 + g*8 + i]
    bf16x8 pb[2];
#pragma unroll
    for (int kk = 0; kk < 2; ++kk)
#pragma unroll
      for (int i = 0; i < 4; ++i) {
        pb[kk][i] = (__bf16)p[2 * kk][i];
        pb[kk][4 + i] = (__bf16)p[2 * kk + 1][i];
      }

    // PV: Oa[db] += V^T-frag(db,kk) * pb[kk]
#pragma unroll
    for (int db = 0; db < 4; ++db)
#pragma unroll
      for (int kk = 0; kk < 2; ++kk) {
        bf16x8 vf = *(const bf16x8*)&Vs[(db * 16 + c) * 72 + kk * 32 + g * 8];
        Oa[db] = MFMA16(vf, pb[kk], Oa[db]);
      }
    __syncthreads();  // protect Ks/Vs before next staging
  }

  // finalize + write: q = q0 + c, d = db*16 + g*4 + reg -> bf16x4 stores
  const float inv = 1.0f / lrow;
  const size_t rowq = (size_t)(b * SEQ) + q0 + c;
#pragma unroll
  for (int db = 0; db < 4; ++db) {
    bf16x4 o;
#pragma unroll
    for (int reg = 0; reg < 4; ++reg) o[reg] = (__bf16)(Oa[db][reg] * inv);
    *(bf16x4*)&attn2b[rowq * TD + h * HD + db * 16 + g * 4] = o;
  }
}

// ---------------------------------------------------------------------------
extern "C" void kernel_launch(void* const* d_in, const int* in_sizes, int n_in,
                              void* d_out, int out_size, void* d_ws,
                              size_t ws_size, hipStream_t stream) {
  const float* x = (const float*)d_in[0];      // (8,1024,768)
  const float* W_qkv = (const float*)d_in[1];  // (768,2304)
  const float* W_out = (const float*)d_in[2];  // (768,768)
  const float* b_out = (const float*)d_in[3];  // (768,)
  float* out = (float*)d_out;

  // Workspace (bf16 elems): xb | wqkvt | woutt | qkvb | vtb | attn2b  (~80 MB)
  __bf16* xb = (__bf16*)d_ws;
  __bf16* wqkvt = xb + (size_t)NB * SEQ * TD;           // 6291456
  __bf16* woutt = wqkvt + (size_t)QKVC * TD;            // 1769472
  __bf16* qkvb = woutt + (size_t)TD * TD;               // 589824
  __bf16* vtb = qkvb + (size_t)NB * SEQ * QKVC;         // 18874368
  __bf16* attn2b = vtb + (size_t)NB * NH * HD * SEQ;    // 6291456

  // casts / transposes
  cast_f32_bf16<<<(NB * SEQ * TD / 4 + 255) / 256, 256, 0, stream>>>(x, xb, NB * SEQ * TD / 4);
  wtrans<<<dim3(QKVC / 32, TD / 32), 256, 0, stream>>>(W_qkv, wqkvt, TD, QKVC);
  wtrans<<<dim3(TD / 32, TD / 32), 256, 0, stream>>>(W_out, woutt, TD, TD);

  // GEMM1: (8192x768) @ (768x2304) -> qkv bf16 (flat buffer == reshaped view)
  gemm_mfma<1><<<dim3(QKVC / 128, NB * SEQ / 128), 256, 0, stream>>>(
      xb, wqkvt, nullptr, qkvb, NB * SEQ, QKVC, TD);

  // V transpose (per b,h contiguous blocks)
  vtrans<<<dim3(SEQ / 128, NH, NB), 256, 0, stream>>>(qkvb, vtb);

  // attention
  attn_mfma<<<dim3(SEQ / 64, NH, NB), 256, 0, stream>>>(qkvb, vtb, attn2b);

  // GEMM2: (8192x768) @ (768x768) + bias -> out fp32
  gemm_mfma<0><<<dim3(TD / 128, NB * SEQ / 128), 256, 0, stream>>>(
      attn2b, woutt, b_out, out, NB * SEQ, TD, TD);
}

// Round 6
// 158.027 us; speedup vs baseline: 8.3197x; 1.0378x over previous
//
#include <hip/hip_runtime.h>
#include <math.h>

// Problem constants
static constexpr int NB   = 8;     // batch
static constexpr int SEQ  = 1024;  // sequence length
static constexpr int TD   = 768;   // token dim
static constexpr int NH   = 12;    // heads
static constexpr int HD   = 64;    // head dim
static constexpr int QKVC = 3 * NH * HD;  // 2304

// Reference reshape quirk: qkv.reshape(b,3,H,n,D) reinterprets the per-batch
// flat (N*2304) row-major buffer as contiguous thirds. Per (b, t, h):
//   elem(t,h,n,d) = qkv_flat[b*2359296 + t*786432 + h*65536 + n*64 + d]
static constexpr size_t BATCH_ELEMS = (size_t)SEQ * QKVC;    // 2359296
static constexpr size_t THIRD_ELEMS = (size_t)NH * SEQ * HD; // 786432
static constexpr size_t HEAD_ELEMS  = (size_t)SEQ * HD;      // 65536

typedef __bf16 bf16x8 __attribute__((ext_vector_type(8)));
typedef __bf16 bf16x4 __attribute__((ext_vector_type(4)));
typedef float  f32x4  __attribute__((ext_vector_type(4)));

#define MFMA16(a, b, c) __builtin_amdgcn_mfma_f32_16x16x32_bf16((a), (b), (c), 0, 0, 0)

// 0.125 (attention scale) * log2(e), folded into exp2
static constexpr float SCL2E = 0.18033688011112042f;

// async global->LDS, 16B per lane; lds dest must be wave-uniform base (+lane*16)
__device__ __forceinline__ void gload_lds16(const void* g, void* l) {
  __builtin_amdgcn_global_load_lds(
      (const __attribute__((address_space(1))) unsigned int*)g,
      (__attribute__((address_space(3))) unsigned int*)l, 16, 0, 0);
}

// ---------------------------------------------------------------------------
// cast fp32 -> bf16, 4 elems/thread
// ---------------------------------------------------------------------------
__global__ __launch_bounds__(256) void cast_f32_bf16(const float* __restrict__ in,
                                                     __bf16* __restrict__ out, int n4) {
  int i = blockIdx.x * 256 + threadIdx.x;
  if (i < n4) {
    float4 v = ((const float4*)in)[i];
    bf16x4 o;
    o[0] = (__bf16)v.x; o[1] = (__bf16)v.y; o[2] = (__bf16)v.z; o[3] = (__bf16)v.w;
    ((bf16x4*)out)[i] = o;
  }
}

// ---------------------------------------------------------------------------
// transpose + cast: W (K x N f32) -> Wt (N x K bf16). 32x32 tiles.
// ---------------------------------------------------------------------------
__global__ __launch_bounds__(256) void wtrans(const float* __restrict__ W,
                                              __bf16* __restrict__ Wt, int K, int N) {
  __shared__ float T[32 * 33];
  const int tid = threadIdx.x;
  const int k0 = blockIdx.y * 32, n0 = blockIdx.x * 32;
#pragma unroll
  for (int i = 0; i < 4; ++i) {
    int idx = tid + i * 256;
    int kk = idx >> 5, nn = idx & 31;
    T[kk * 33 + nn] = W[(size_t)(k0 + kk) * N + n0 + nn];
  }
  __syncthreads();
#pragma unroll
  for (int i = 0; i < 4; ++i) {
    int idx = tid + i * 256;
    int nn = idx >> 5, kk = idx & 31;
    Wt[(size_t)(n0 + nn) * K + k0 + kk] = (__bf16)T[kk * 33 + nn];
  }
}

// ---------------------------------------------------------------------------
// Transpose V third: per (b,h), V is a contiguous (1024,64) bf16 block.
// Produce Vt[b][h][d][n] (d-major, n contiguous) for the PV A-fragments.
// ---------------------------------------------------------------------------
__global__ __launch_bounds__(256) void vtrans(const __bf16* __restrict__ qkvb,
                                              __bf16* __restrict__ vtb) {
  const int nt = blockIdx.x;  // 0..7
  const int h = blockIdx.y;   // 0..11
  const int b = blockIdx.z;   // 0..7
  __shared__ __bf16 T[128 * 72];
  const int tid = threadIdx.x;
  const int n0 = nt * 128;
  const __bf16* Vb = qkvb + (size_t)b * BATCH_ELEMS + 2 * THIRD_ELEMS + (size_t)h * HEAD_ELEMS;
#pragma unroll
  for (int i = 0; i < 4; ++i) {
    int ch = tid + i * 256;
    int row = ch >> 3, c8 = ch & 7;
    *(bf16x8*)&T[row * 72 + c8 * 8] = *(const bf16x8*)&Vb[(size_t)(n0 + row) * HD + c8 * 8];
  }
  __syncthreads();
#pragma unroll
  for (int i = 0; i < 4; ++i) {
    int ch = tid + i * 256;
    int d = ch >> 4, n8 = ch & 15;
    bf16x8 v;
#pragma unroll
    for (int j = 0; j < 8; ++j) v[j] = T[(n8 * 8 + j) * 72 + d];
    *(bf16x8*)&vtb[((size_t)((b * NH + h) * HD) + d) * SEQ + n0 + n8 * 8] = v;
  }
}

// ---------------------------------------------------------------------------
// bf16 MFMA GEMM: C[M,N] = A[M,K] @ Bt[N,K]^T  (+ bias, fp32 out) or bf16 out.
// 128x128 tile, BK=32, 256 threads = 4 waves (2x2 of 64x64).
// m97 structure: global_load_lds width=16 into LINEAR [128][32] LDS.
// Fragment reads: dword bank-group = 4*(r&1)+g -> exactly the 8-cycle floor.
// ---------------------------------------------------------------------------
template <int OUT_BF16>
__global__ __launch_bounds__(256) void gemm_mfma(const __bf16* __restrict__ A,
                                                 const __bf16* __restrict__ Bt,
                                                 const float* __restrict__ bias,
                                                 void* __restrict__ C,
                                                 int M, int N, int K) {
  __shared__ __bf16 As[128 * 32];
  __shared__ __bf16 Bs[128 * 32];
  const int tid = threadIdx.x;
  const int lane = tid & 63;
  const int wid = tid >> 6;
  const int wr = wid >> 1, wc = wid & 1;
  const int r = lane & 15, g = lane >> 4;
  const size_t bm = (size_t)blockIdx.y * 128;
  const size_t bn = (size_t)blockIdx.x * 128;

  // staging: wave wid covers LDS rows [wid*32, wid*32+32); lane -> 16B chunk
  const int srow = lane >> 2;        // 0..15 within 16-row group
  const int scol = (lane & 3) * 8;   // bf16 col

  f32x4 acc[4][4];
#pragma unroll
  for (int mi = 0; mi < 4; ++mi)
#pragma unroll
    for (int nj = 0; nj < 4; ++nj) acc[mi][nj] = (f32x4){0.f, 0.f, 0.f, 0.f};

  for (int k0 = 0; k0 < K; k0 += 32) {
#pragma unroll
    for (int j = 0; j < 2; ++j) {
      const int rowbase = wid * 32 + j * 16;
      gload_lds16(&A[(bm + rowbase + srow) * K + k0 + scol], &As[rowbase * 32]);
      gload_lds16(&Bt[(bn + rowbase + srow) * K + k0 + scol], &Bs[rowbase * 32]);
    }
    __syncthreads();
    bf16x8 af[4], bf[4];
#pragma unroll
    for (int mi = 0; mi < 4; ++mi)
      af[mi] = *(const bf16x8*)&As[(wr * 64 + mi * 16 + r) * 32 + g * 8];
#pragma unroll
    for (int nj = 0; nj < 4; ++nj)
      bf[nj] = *(const bf16x8*)&Bs[(wc * 64 + nj * 16 + r) * 32 + g * 8];
#pragma unroll
    for (int mi = 0; mi < 4; ++mi)
#pragma unroll
      for (int nj = 0; nj < 4; ++nj)
        acc[mi][nj] = MFMA16(af[mi], bf[nj], acc[mi][nj]);
    __syncthreads();
  }

  const int orow0 = g * 4;
  const int ocol = r;
#pragma unroll
  for (int mi = 0; mi < 4; ++mi)
#pragma unroll
    for (int nj = 0; nj < 4; ++nj)
#pragma unroll
      for (int reg = 0; reg < 4; ++reg) {
        size_t rrow = bm + wr * 64 + mi * 16 + orow0 + reg;
        size_t ccol = bn + wc * 64 + nj * 16 + ocol;
        float v = acc[mi][nj][reg];
        if (OUT_BF16)
          ((__bf16*)C)[rrow * N + ccol] = (__bf16)v;
        else
          ((float*)C)[rrow * N + ccol] = v + bias[ccol];
      }
}

// ---------------------------------------------------------------------------
// bf16 MFMA flash attention, v3: in-register P (round 5) + fragment-linear
// LDS (zero bank conflicts, zero per-read addr VALU) + double-buffered
// early-issue staging (one barrier per kv-tile).
//
// LDS layout: 16B chunk idx = (t2f)*64 + lane holds exactly the bf16x8 that
// lane needs for MFMA fragment group t2f. Reads are base + lane*16 + imm.
// Staging permutation folded into per-thread GLOBAL source addresses.
// ---------------------------------------------------------------------------
__global__ __launch_bounds__(256) void attn_mfma(const __bf16* __restrict__ qkvb,
                                                 const __bf16* __restrict__ vtb,
                                                 __bf16* __restrict__ attn2b) {
  const int qt = blockIdx.x;  // 0..15
  const int h = blockIdx.y;   // 0..11
  const int b = blockIdx.z;   // 0..7
  const int tid = threadIdx.x;
  const int lane = tid & 63;
  const int w = tid >> 6;
  const int c = lane & 15, g = lane >> 4;

  __shared__ __bf16 KsF[2][4096];  // [buf][(t2f*64 + lane)*8]
  __shared__ __bf16 VsF[2][4096];

  const __bf16* Qb = qkvb + (size_t)b * BATCH_ELEMS + (size_t)h * HEAD_ELEMS;
  const __bf16* Kb = Qb + THIRD_ELEMS;
  const __bf16* Vtb = vtb + (size_t)((b * NH + h) * HD) * SEQ;
  const int q0 = qt * 64 + w * 16;

  // Per-thread staging decode: thread stages chunks idx = (i*4+w)*64 + lane.
  int kOffG[2], vOffG[2], sOffL[2];
#pragma unroll
  for (int i = 0; i < 2; ++i) {
    const int t2f = i * 4 + w;
    const int t = t2f >> 1, f = t2f & 1;
    // permuted K row matching the QK^T fragment assignment
    const int krow = ((t >> 1) << 5) | ((c >> 2) << 3) | ((t & 1) << 2) | (c & 3);
    kOffG[i] = krow * HD + f * 32 + g * 8;
    const int db = t2f >> 1, kk = t2f & 1;
    vOffG[i] = (db * 16 + c) * SEQ + kk * 32 + g * 8;
    sOffL[i] = (t2f * 64 + lane) * 8;
  }

  // Q B-frags (lane c+16g holds Q[q0+c][f*32 + g*8 + i]) — natural load
  bf16x8 qf[2];
#pragma unroll
  for (int f = 0; f < 2; ++f)
    qf[f] = *(const bf16x8*)&Qb[(size_t)(q0 + c) * HD + f * 32 + g * 8];

  f32x4 Oa[4];  // O^T accum: Oa[db][reg] = O[q=c][d = db*16 + g*4 + reg]
#pragma unroll
  for (int db = 0; db < 4; ++db) Oa[db] = (f32x4){0.f, 0.f, 0.f, 0.f};
  float mrow = -3.0e38f, mrowS = -3.0e38f * SCL2E, lrow = 0.f;

  bf16x8 kreg[2], vreg[2];
  // prologue: stage tile 0
#pragma unroll
  for (int i = 0; i < 2; ++i) {
    kreg[i] = *(const bf16x8*)&Kb[kOffG[i]];
    vreg[i] = *(const bf16x8*)&Vtb[vOffG[i]];
  }
#pragma unroll
  for (int i = 0; i < 2; ++i) {
    *(bf16x8*)&KsF[0][sOffL[i]] = kreg[i];
    *(bf16x8*)&VsF[0][sOffL[i]] = vreg[i];
  }
  __syncthreads();

  int cur = 0;
  for (int it = 0; it < SEQ / 64; ++it) {
    // issue next tile's global loads early (latency hides under compute)
    if (it < SEQ / 64 - 1) {
      const int kv0 = (it + 1) * 64;
#pragma unroll
      for (int i = 0; i < 2; ++i) {
        kreg[i] = *(const bf16x8*)&Kb[(size_t)kv0 * HD + kOffG[i]];
        vreg[i] = *(const bf16x8*)&Vtb[kv0 + vOffG[i]];
      }
    }

    // S^T tiles: sa[t][reg] = S[q=c][kv = (t>>1)*32 + g*8 + (t&1)*4 + reg]
    f32x4 sa[4];
#pragma unroll
    for (int t = 0; t < 4; ++t) sa[t] = (f32x4){0.f, 0.f, 0.f, 0.f};
#pragma unroll
    for (int t = 0; t < 4; ++t)
#pragma unroll
      for (int f = 0; f < 2; ++f) {
        bf16x8 kf = *(const bf16x8*)&KsF[cur][(t * 2 + f) * 512 + lane * 8];
        sa[t] = MFMA16(kf, qf[f], sa[t]);
      }

    // online softmax: lane owns q-row c; cross-g reduce via shfl 16/32
    float tm = -3.0e38f;
#pragma unroll
    for (int t = 0; t < 4; ++t)
#pragma unroll
      for (int reg = 0; reg < 4; ++reg) tm = fmaxf(tm, sa[t][reg]);
    tm = fmaxf(tm, __shfl_xor(tm, 16));
    tm = fmaxf(tm, __shfl_xor(tm, 32));
    if (!__all(tm <= mrow)) {  // exact skip: alpha==1 when max didn't grow
      const float mnew = fmaxf(mrow, tm);
      const float mnewS = mnew * SCL2E;
      const float alpha = __builtin_exp2f(mrowS - mnewS);
      lrow *= alpha;
#pragma unroll
      for (int db = 0; db < 4; ++db)
#pragma unroll
        for (int reg = 0; reg < 4; ++reg) Oa[db][reg] *= alpha;
      mrow = mnew;
      mrowS = mnewS;
    }
    float rs = 0.f;
    float p[4][4];
#pragma unroll
    for (int t = 0; t < 4; ++t)
#pragma unroll
      for (int reg = 0; reg < 4; ++reg) {
        float pv = __builtin_exp2f(__builtin_fmaf(sa[t][reg], SCL2E, -mrowS));
        p[t][reg] = pv;
        rs += pv;
      }
    rs += __shfl_xor(rs, 16);
    rs += __shfl_xor(rs, 32);
    lrow += rs;

    // pack P into PV B-frags: pb[kk][i] = P[c][kv0 + kk*32 + g*8 + i]
    bf16x8 pb[2];
#pragma unroll
    for (int kk = 0; kk < 2; ++kk)
#pragma unroll
      for (int i = 0; i < 4; ++i) {
        pb[kk][i] = (__bf16)p[2 * kk][i];
        pb[kk][4 + i] = (__bf16)p[2 * kk + 1][i];
      }

    // PV: Oa[db] += V^T-frag(db,kk) * pb[kk]
#pragma unroll
    for (int db = 0; db < 4; ++db)
#pragma unroll
      for (int kk = 0; kk < 2; ++kk) {
        bf16x8 vf = *(const bf16x8*)&VsF[cur][(db * 2 + kk) * 512 + lane * 8];
        Oa[db] = MFMA16(vf, pb[kk], Oa[db]);
      }

    // write next tile into the other buffer (read in next iter after barrier)
    if (it < SEQ / 64 - 1) {
      const int nxt = cur ^ 1;
#pragma unroll
      for (int i = 0; i < 2; ++i) {
        *(bf16x8*)&KsF[nxt][sOffL[i]] = kreg[i];
        *(bf16x8*)&VsF[nxt][sOffL[i]] = vreg[i];
      }
    }
    __syncthreads();
    cur ^= 1;
  }

  // finalize + write: q = q0 + c, d = db*16 + g*4 + reg -> bf16x4 stores
  const float inv = 1.0f / lrow;
  const size_t rowq = (size_t)(b * SEQ) + q0 + c;
#pragma unroll
  for (int db = 0; db < 4; ++db) {
    bf16x4 o;
#pragma unroll
    for (int reg = 0; reg < 4; ++reg) o[reg] = (__bf16)(Oa[db][reg] * inv);
    *(bf16x4*)&attn2b[rowq * TD + h * HD + db * 16 + g * 4] = o;
  }
}

// ---------------------------------------------------------------------------
extern "C" void kernel_launch(void* const* d_in, const int* in_sizes, int n_in,
                              void* d_out, int out_size, void* d_ws,
                              size_t ws_size, hipStream_t stream) {
  const float* x = (const float*)d_in[0];      // (8,1024,768)
  const float* W_qkv = (const float*)d_in[1];  // (768,2304)
  const float* W_out = (const float*)d_in[2];  // (768,768)
  const float* b_out = (const float*)d_in[3];  // (768,)
  float* out = (float*)d_out;

  // Workspace (bf16 elems): xb | wqkvt | woutt | qkvb | vtb | attn2b  (~80 MB)
  __bf16* xb = (__bf16*)d_ws;
  __bf16* wqkvt = xb + (size_t)NB * SEQ * TD;           // 6291456
  __bf16* woutt = wqkvt + (size_t)QKVC * TD;            // 1769472
  __bf16* qkvb = woutt + (size_t)TD * TD;               // 589824
  __bf16* vtb = qkvb + (size_t)NB * SEQ * QKVC;         // 18874368
  __bf16* attn2b = vtb + (size_t)NB * NH * HD * SEQ;    // 6291456

  // casts / transposes
  cast_f32_bf16<<<(NB * SEQ * TD / 4 + 255) / 256, 256, 0, stream>>>(x, xb, NB * SEQ * TD / 4);
  wtrans<<<dim3(QKVC / 32, TD / 32), 256, 0, stream>>>(W_qkv, wqkvt, TD, QKVC);
  wtrans<<<dim3(TD / 32, TD / 32), 256, 0, stream>>>(W_out, woutt, TD, TD);

  // GEMM1: (8192x768) @ (768x2304) -> qkv bf16 (flat buffer == reshaped view)
  gemm_mfma<1><<<dim3(QKVC / 128, NB * SEQ / 128), 256, 0, stream>>>(
      xb, wqkvt, nullptr, qkvb, NB * SEQ, QKVC, TD);

  // V transpose (per b,h contiguous blocks)
  vtrans<<<dim3(SEQ / 128, NH, NB), 256, 0, stream>>>(qkvb, vtb);

  // attention
  attn_mfma<<<dim3(SEQ / 64, NH, NB), 256, 0, stream>>>(qkvb, vtb, attn2b);

  // GEMM2: (8192x768) @ (768x768) + bias -> out fp32
  gemm_mfma<0><<<dim3(TD / 128, NB * SEQ / 128), 256, 0, stream>>>(
      attn2b, woutt, b_out, out, NB * SEQ, TD, TD);
}